// Round 1
// 243.135 us; speedup vs baseline: 1.0244x; 1.0244x over previous
//
#include <hip/hip_runtime.h>

// SelfAttentiveLBLBiLM on MI355X — round 8.
// r7 post-mortem: QKV GEMM 597 TF, MfmaUtil 22%, bank conflicts 0, HBM 25%.
// Bottleneck = m97-class serial stage->drain->compute loop (vmcnt(0) every
// K-step). Now: QKV + highway GEMMs ported to the 256x256 8-phase schedule
// (T2 st_16x32 swizzle + T3/T4 counted vmcnt(6) + T5 setprio):
//  - 8 waves (512 thr), BK=64, 128 KiB LDS (2 dbuf x 2 halves x A,B)
//  - each phase: ds-read quadrant | stage 1 half-tile | bar | 16 MFMA | bar
//  - refill invariant: a half-slot is restaged exactly one phase after its
//    last ds_read (safe via the inter-phase barrier); vmcnt(6) at ph4/ph8
//    only (last iter: vmcnt(0) at ph4 since tail issues are skipped).
//  - hw weight interleave remapped so (nl,g) pairs share a wave at 256-tile.
// Proj stays on the 128^2 kernel (N=512 -> only 128 blocks at 256^2).
// Dispatches: prep, qkv gemm256, attn, proj+rel gemm, hw gemm256 x2.

#define B_ 8
#define S_ 1024
#define D_ 512
#define H_ 8
#define DK_ 64
#define WIDTH_ 8
#define S2_ 1040
#define NHW_ 2

typedef short bf16x8 __attribute__((ext_vector_type(8)));
typedef float f32x4 __attribute__((ext_vector_type(4)));

__device__ __forceinline__ float us2f(unsigned short u) {
  union { unsigned int i; float f; } c; c.i = ((unsigned int)u) << 16; return c.f;
}
__device__ __forceinline__ unsigned short f2us(float f) {
  union { float f; unsigned int i; } c; c.f = f;
  unsigned int x = c.i;
  return (unsigned short)((x + 0x7fffu + ((x >> 16) & 1u)) >> 16);
}
__device__ __forceinline__ unsigned int pack2(float a, float b) {
  return (unsigned int)f2us(a) | ((unsigned int)f2us(b) << 16);
}
__device__ __forceinline__ void async16(const void* g, void* l) {
  __builtin_amdgcn_global_load_lds(
      (const __attribute__((address_space(1))) void*)g,
      (__attribute__((address_space(3))) void*)l, 16, 0, 0);
}
__device__ __forceinline__ void unpack8(uint4 u, float* f) {
  unsigned int w[4] = {u.x, u.y, u.z, u.w};
  #pragma unroll
  for (int c = 0; c < 4; ++c) {
    union { unsigned int i; float g; } lo, hi;
    lo.i = w[c] << 16;
    hi.i = w[c] & 0xffff0000u;
    f[2 * c] = lo.g;
    f[2 * c + 1] = hi.g;
  }
}

// ---------------------------------------------------------------------------
// Prep mega-kernel. blockIdx.x ranges:
//  [0,2048): attn weight transpose, 8 slices (side=sl>>2, slice=sl&3), 16x16
//  [2048,4096): hw weight transpose+interleave (256-tile pairing), 4 slices
//  [4096,6188): build new_in (+ qkv bias tail)
__global__ __launch_bounds__(256) void k_prep(
    const float* __restrict__ x,
    const float* __restrict__ lpad, const float* __restrict__ rpad,
    const float* __restrict__ lW, const float* __restrict__ rW,
    const float* __restrict__ lb, const float* __restrict__ rb,
    const float* __restrict__ lhwW, const float* __restrict__ rhwW,
    unsigned short* __restrict__ WTall, unsigned short* __restrict__ WTp,
    unsigned short* __restrict__ hWT,
    unsigned short* __restrict__ nin, float* __restrict__ qkvbias)
{
  __shared__ float tile[32][33];
  const size_t DD = (size_t)D_ * D_;
  int bx = blockIdx.x;
  int tx = threadIdx.x & 31, ty = threadIdx.x >> 5;

  if (bx < 2048) {                     // ---- attn transpose
    int sl = bx >> 8, rem = bx & 255;
    int side = sl >> 2, slice = sl & 3;
    int c0 = (rem & 15) * 32, r0 = (rem >> 4) * 32;
    const float* src = (side ? rW : lW) + (size_t)slice * DD;
    unsigned short* dst = (slice < 3) ? WTall + (size_t)(side * 3 + slice) * DD
                                      : WTp + (size_t)side * DD;
    #pragma unroll
    for (int i = 0; i < 4; ++i)
      tile[ty + i * 8][tx] = src[(size_t)(r0 + ty + i * 8) * D_ + c0 + tx];
    __syncthreads();
    #pragma unroll
    for (int i = 0; i < 4; ++i)
      dst[(size_t)(c0 + ty + i * 8) * D_ + r0 + tx] = f2us(tile[tx][ty + i * 8]);
    return;
  }
  if (bx < 4096) {                     // ---- hw transpose + interleave
    int idx = bx - 2048;
    int sl = idx >> 9, rem = idx & 511;    // sl: side*2+layer
    int c0 = (rem & 31) * 32, r0 = (rem >> 5) * 32;
    const float* src = ((sl >> 1) ? rhwW : lhwW) + (size_t)(sl & 1) * 512 * 1024;
    unsigned short* dst = hWT + (size_t)sl * 1024 * 512;
    #pragma unroll
    for (int i = 0; i < 4; ++i)
      tile[ty + i * 8][tx] = src[(size_t)(r0 + ty + i * 8) * 1024 + c0 + tx];
    __syncthreads();
    // 256-tile pairing: orig col c (nl: c<512, g: c>=512) -> BT row q such
    // that nl x and g x land in ni=2np / 2np+1 of the same wave wn.
    #pragma unroll
    for (int i = 0; i < 4; ++i) {
      int c = c0 + ty + i * 8;
      int cm = c & 511;
      int j = cm >> 4;                       // 16-col block of x, 0..31
      int jl = j & 7;
      int Bq = ((jl >> 2) << 3) + (jl & 3) + ((c >= 512) ? 4 : 0);
      int q = (j >> 3) * 256 + Bq * 16 + (cm & 15);
      dst[(size_t)q * 512 + r0 + tx] = f2us(tile[tx][ty + i * 8]);
    }
    return;
  }
  // ---- build new_in + bias tail
  int gid = (bx - 4096) * 256 + threadIdx.x;
  const int NTH = B_ * S2_ * 64;       // 532,480
  if (gid >= NTH) {
    int t = gid - NTH;
    if (t < 1536) qkvbias[t] = lb[t];
    else if (t < 3072) qkvbias[t] = rb[t - 1536];
    return;
  }
  int c8 = (gid & 63) << 3;
  int row = gid >> 6;
  int b = row / S2_;
  int t = row - b * S2_;
  const float* src;
  if (t < WIDTH_)            src = lpad + (size_t)t * D_ + c8;
  else if (t >= S_ + WIDTH_) src = rpad + (size_t)(t - S_ - WIDTH_) * D_ + c8;
  else                       src = x + ((size_t)b * S_ + (t - WIDTH_)) * D_ + c8;
  float4 a = *reinterpret_cast<const float4*>(src);
  float4 c = *reinterpret_cast<const float4*>(src + 4);
  uint4 o;
  o.x = pack2(a.x, a.y); o.y = pack2(a.z, a.w);
  o.z = pack2(c.x, c.y); o.w = pack2(c.z, c.w);
  *reinterpret_cast<uint4*>(nin + (size_t)row * D_ + c8) = o;
}

// ---------------------------------------------------------------------------
// 256x256 8-phase GEMM, K=512. C(M,N) = A(M,K) @ BT(N,K)^T, fused epilogue:
//  EPI=0: +bias(N), bf16 store stride N (QKV)
//  EPI=1: highway gate -> bf16 (z*MS + row*512 + x)
//  EPI=2: highway gate -> f32  (row*1024 + z*512 + x)
// 8 waves = 2(M) x 4(N); per-wave 128x64 out; LDS 128 KiB:
//  A: [buf][half] 128x64 bf16 (16 KB each), B likewise at +64 KB.
// st_16x32 swizzle: byte ^= ((byte>>9)&1)<<5 within each 1 KB subtile,
// applied via pre-swizzled global source (linear global_load_lds dest) and
// swizzled ds_read addresses.
template <int EPI>
__global__ __launch_bounds__(512, 2) void k_gemm256(
    const unsigned short* __restrict__ Abase, size_t aStrZ,
    const unsigned short* __restrict__ BTbase, size_t bStrZ,
    const float* __restrict__ bias0, const float* __restrict__ bias1,
    unsigned short* __restrict__ Cbf, float* __restrict__ Cfp,
    int M, int N)
{
  __shared__ __align__(16) unsigned short smem[65536];   // 128 KiB
  const int tid = threadIdx.x;
  const int w = tid >> 6, l = tid & 63;
  const int wm = w >> 2, wn = w & 3;
  const int fl = l & 15, fq = l >> 4;
  const int z = blockIdx.z;
  const unsigned short* A = Abase + (size_t)z * aStrZ;
  const unsigned short* BT = BTbase + (size_t)z * bStrZ;
  const int bm = blockIdx.y * 256, bn = blockIdx.x * 256;

  // frag-read constants (short offsets). Row rh = block*16+fl =>
  // swizzle bit = (rh>>2)&1 = (fl>>2)&1 (thread-constant).
  const int xorv = ((fl >> 2) & 1) << 5;
  const int cs0 = ((fq * 16) ^ xorv) >> 1;        // k-slice 0
  const int cs1 = ((64 + fq * 16) ^ xorv) >> 1;   // k-slice 1

  // stage-source constants: LDS chunk pos p=(2w+i)*1024 + l*16, inverse-
  // swizzled source element (row rr, col ce) within the 8-row chunk.
  const int loff = (l * 16) ^ ((l >= 32) ? 32 : 0);
  const int rr = loff >> 7;
  const int ce = (loff & 127) >> 1;
  const unsigned short* gA[2][2];
  const unsigned short* gB[2][2];
  #pragma unroll
  for (int i = 0; i < 2; ++i)
    #pragma unroll
    for (int h = 0; h < 2; ++h) {
      int ra = bm + h * 128 + (2 * w + i) * 8 + rr;
      if (ra > M - 1) ra = M - 1;            // M=8320 tail clamp (QKV)
      gA[i][h] = A + (size_t)ra * 512 + ce;
      int rb = bn + h * 128 + (2 * w + i) * 8 + rr;
      gB[i][h] = BT + (size_t)rb * 512 + ce;
    }

  f32x4 acc[8][4];
  #pragma unroll
  for (int mi = 0; mi < 8; ++mi)
    #pragma unroll
    for (int ni = 0; ni < 4; ++ni) acc[mi][ni] = (f32x4){0.f, 0.f, 0.f, 0.f};

  bf16x8 ar[4][2], br[2][2];

#define BAR() __builtin_amdgcn_s_barrier()
#define STGA(buf, h, kt) do { \
    async16(gA[0][h] + (kt) * 64, &smem[((buf) * 2 + (h)) * 8192 + (2 * w) * 512]); \
    async16(gA[1][h] + (kt) * 64, &smem[((buf) * 2 + (h)) * 8192 + (2 * w + 1) * 512]); } while (0)
#define STGB(buf, h, kt) do { \
    async16(gB[0][h] + (kt) * 64, &smem[32768 + ((buf) * 2 + (h)) * 8192 + (2 * w) * 512]); \
    async16(gB[1][h] + (kt) * 64, &smem[32768 + ((buf) * 2 + (h)) * 8192 + (2 * w + 1) * 512]); } while (0)
#define LDA(buf, h) do { const unsigned short* p_ = &smem[((buf) * 2 + (h)) * 8192]; \
    _Pragma("unroll") for (int m4 = 0; m4 < 4; ++m4) { \
      int ro_ = ((2 * m4 + wm) * 16 + fl) * 64; \
      ar[m4][0] = *reinterpret_cast<const bf16x8*>(p_ + ro_ + cs0); \
      ar[m4][1] = *reinterpret_cast<const bf16x8*>(p_ + ro_ + cs1); } } while (0)
#define LDB(buf, h) do { const unsigned short* p_ = &smem[32768 + ((buf) * 2 + (h)) * 8192]; \
    _Pragma("unroll") for (int n2 = 0; n2 < 2; ++n2) { \
      int ro_ = ((4 * n2 + wn) * 16 + fl) * 64; \
      br[n2][0] = *reinterpret_cast<const bf16x8*>(p_ + ro_ + cs0); \
      br[n2][1] = *reinterpret_cast<const bf16x8*>(p_ + ro_ + cs1); } } while (0)
#define QUAD(miH, niH) do { __builtin_amdgcn_s_setprio(1); \
    _Pragma("unroll") for (int m4 = 0; m4 < 4; ++m4) \
      _Pragma("unroll") for (int n2 = 0; n2 < 2; ++n2) \
        _Pragma("unroll") for (int s_ = 0; s_ < 2; ++s_) \
          acc[(miH) * 4 + m4][(niH) * 2 + n2] = __builtin_amdgcn_mfma_f32_16x16x32_bf16( \
              ar[m4][s_], br[n2][s_], acc[(miH) * 4 + m4][(niH) * 2 + n2], 0, 0, 0); \
    __builtin_amdgcn_s_setprio(0); } while (0)

  // prologue: T0 {A0,B0,B1,A1} -> buf0, T1 {A0,B1,A1} -> buf1 (B0 at I1).
  STGA(0, 0, 0); STGB(0, 0, 0); STGB(0, 1, 0); STGA(0, 1, 0);
  STGA(1, 0, 1); STGB(1, 1, 1); STGA(1, 1, 1);
  asm volatile("s_waitcnt vmcnt(6)" ::: "memory");   // T0 fully landed
  BAR();

  #pragma unroll 1
  for (int it = 0; it < 4; ++it) {
    const int t1 = 2 * it + 1, t2 = 2 * it + 2, t3 = 2 * it + 3;
    // ph1: quad(0,0) buf0 | I1: t1.B0 -> buf1.B0 (last read prev ph8)
    LDA(0, 0); LDB(0, 0);
    STGB(1, 0, t1);
    BAR(); QUAD(0, 0); BAR();
    // ph2: quad(0,1) buf0 | I2: t2.A0 -> buf0.A0 (last read ph1)
    LDB(0, 1);
    if (t2 < 8) STGA(0, 0, t2);
    BAR(); QUAD(0, 1); BAR();
    // ph3: quad(1,1) buf0 | I3: t2.B1 -> buf0.B1 (last read ph2)
    LDA(0, 1);
    if (t2 < 8) STGB(0, 1, t2);
    BAR(); QUAD(1, 1); BAR();
    // ph4: quad(1,0) buf0 | I4: t2.A1 -> buf0.A1 (last read ph3)
    LDB(0, 0);
    if (t2 < 8) STGA(0, 1, t2);
    BAR(); QUAD(1, 0);
    if (it < 3) asm volatile("s_waitcnt vmcnt(6)" ::: "memory");
    else        asm volatile("s_waitcnt vmcnt(0)" ::: "memory");
    BAR();
    // ph5: quad(0,0) buf1 | I5: t2.B0 -> buf0.B0 (last read ph4)
    LDA(1, 0); LDB(1, 0);
    if (t2 < 8) STGB(0, 0, t2);
    BAR(); QUAD(0, 0); BAR();
    // ph6: quad(0,1) buf1 | I6: t3.A0 -> buf1.A0 (last read ph5)
    LDB(1, 1);
    if (t3 < 8) STGA(1, 0, t3);
    BAR(); QUAD(0, 1); BAR();
    // ph7: quad(1,1) buf1 | I7: t3.B1 -> buf1.B1 (last read ph6)
    LDA(1, 1);
    if (t3 < 8) STGB(1, 1, t3);
    BAR(); QUAD(1, 1); BAR();
    // ph8: quad(1,0) buf1 | I8: t3.A1 -> buf1.A1 (last read ph7)
    LDB(1, 0);
    if (t3 < 8) STGA(1, 1, t3);
    BAR(); QUAD(1, 0);
    asm volatile("s_waitcnt vmcnt(6)" ::: "memory");
    BAR();
  }
#undef BAR
#undef STGA
#undef STGB
#undef LDA
#undef LDB
#undef QUAD

  // ---- epilogue
  if (EPI == 0) {
    float bv[4];
    #pragma unroll
    for (int ni = 0; ni < 4; ++ni) bv[ni] = bias0[bn + (4 * ni + wn) * 16 + fl];
    #pragma unroll
    for (int mi = 0; mi < 8; ++mi) {
      #pragma unroll
      for (int r = 0; r < 4; ++r) {
        int gr = bm + (2 * mi + wm) * 16 + fq * 4 + r;
        if (gr < M) {
          unsigned short* Cp = Cbf + (size_t)gr * N + bn + wn * 16 + fl;
          #pragma unroll
          for (int ni = 0; ni < 4; ++ni) Cp[ni * 64] = f2us(acc[mi][ni][r] + bv[ni]);
        }
      }
    }
  } else {
    const float* bias = z ? bias1 : bias0;
    const size_t MS = (size_t)B_ * S_ * D_;
    float bnl[2], bg[2]; int xs[2];
    #pragma unroll
    for (int np = 0; np < 2; ++np) {
      xs[np] = (blockIdx.x * 8 + np * 4 + wn) * 16 + fl;
      bnl[np] = bias[xs[np]];
      bg[np]  = bias[512 + xs[np]];
    }
    #pragma unroll
    for (int mi = 0; mi < 8; ++mi) {
      #pragma unroll
      for (int r = 0; r < 4; ++r) {
        int gr = bm + (2 * mi + wm) * 16 + fq * 4 + r;
        #pragma unroll
        for (int np = 0; np < 2; ++np) {
          float nl = fmaxf(acc[mi][2 * np][r] + bnl[np], 0.f);
          float g  = 1.f / (1.f + __expf(-(acc[mi][2 * np + 1][r] + bg[np])));
          float xv = us2f(A[(size_t)gr * 512 + xs[np]]);
          float res = g * xv + (1.f - g) * nl;
          if (EPI == 2) Cfp[(size_t)gr * 1024 + (size_t)z * 512 + xs[np]] = res;
          else Cbf[(size_t)z * MS + (size_t)gr * 512 + xs[np]] = f2us(res);
        }
      }
    }
  }
}

// ---------------------------------------------------------------------------
// Proj GEMM + fused rel-add (unchanged 128^2 structure; N=512 packs badly at
// 256^2). A = ctx (2,8192,512) bf16 compacted; z = side.
__global__ __launch_bounds__(256) void k_gemm_proj(
    const unsigned short* __restrict__ ctx,
    const unsigned short* __restrict__ WTp,    // (2,512,512)
    const unsigned short* __restrict__ nin,    // (B,S2,512)
    const float* __restrict__ lb3, const float* __restrict__ rb3,
    const float* __restrict__ wrel0, const float* __restrict__ wrel1,
    unsigned short* __restrict__ hwx)          // (2,8192,512)
{
  __shared__ unsigned short smem[128 * 136];   // 34.8 KB; staging uses 32 KB
  unsigned short* As = smem;
  unsigned short* Bs = smem + 8192;
  const int K = 512, N = 512;
  const size_t MS = (size_t)B_ * S_ * D_;

  const int z = blockIdx.z;
  const unsigned short* A = ctx + (size_t)z * MS;
  const unsigned short* BT = WTp + (size_t)z * 512 * 512;
  const float* bias = z ? rb3 : lb3;
  const float* wrel = z ? wrel1 : wrel0;
  const int off = z * WIDTH_;

  const int tid = threadIdx.x;
  const int w = tid >> 6;
  const int l = tid & 63;
  const int bm = blockIdx.y * 128;
  const int bn = blockIdx.x * 128;
  const int wrow = (w >> 1) * 64;
  const int wcol = (w & 1) * 64;

  const int lr = l >> 3;
  const int sk = (((l & 7) ^ lr) & 7) * 8;
  const unsigned short* Ap = A + (size_t)(bm + w * 8 + lr) * K + sk;
  const unsigned short* Bp = BT + (size_t)(bn + w * 8 + lr) * K + sk;
  unsigned short* lA = &As[w * 512];
  unsigned short* lB = &Bs[w * 512];
  const size_t K32 = (size_t)32 * K;

  const int fl = l & 15;
  const int fq = l >> 4;
  const int fx = fl & 7;

  f32x4 acc[4][4];
  #pragma unroll
  for (int mi = 0; mi < 4; ++mi)
    #pragma unroll
    for (int ni = 0; ni < 4; ++ni) acc[mi][ni] = (f32x4){0.f, 0.f, 0.f, 0.f};

  for (int k0 = 0; k0 < K; k0 += 64) {
    #pragma unroll
    for (int r = 0; r < 4; ++r) {
      async16(Ap + k0 + r * K32, lA + r * 2048);
      async16(Bp + k0 + r * K32, lB + r * 2048);
    }
    __syncthreads();
    #pragma unroll
    for (int s = 0; s < 2; ++s) {
      bf16x8 af[4], bfr[4];
      #pragma unroll
      for (int mi = 0; mi < 4; ++mi)
        af[mi] = *reinterpret_cast<const bf16x8*>(
            &As[(wrow + mi * 16 + fl) * 64 + (((s * 4 + fq) ^ fx) * 8)]);
      #pragma unroll
      for (int ni = 0; ni < 4; ++ni)
        bfr[ni] = *reinterpret_cast<const bf16x8*>(
            &Bs[(wcol + ni * 16 + fl) * 64 + (((s * 4 + fq) ^ fx) * 8)]);
      #pragma unroll
      for (int mi = 0; mi < 4; ++mi)
        #pragma unroll
        for (int ni = 0; ni < 4; ++ni)
          acc[mi][ni] = __builtin_amdgcn_mfma_f32_16x16x32_bf16(
              af[mi], bfr[ni], acc[mi][ni], 0, 0, 0);
    }
    __syncthreads();
  }

  // stage bias-added tile into LDS (bf16, ld 136)
  float bv[4];
  #pragma unroll
  for (int ni = 0; ni < 4; ++ni) bv[ni] = bias[bn + wcol + ni * 16 + fl];
  const int rbase = (l >> 4) * 4;
  #pragma unroll
  for (int mi = 0; mi < 4; ++mi)
    #pragma unroll
    for (int r = 0; r < 4; ++r)
      #pragma unroll
      for (int ni = 0; ni < 4; ++ni)
        smem[(wrow + mi * 16 + rbase + r) * 136 + wcol + ni * 16 + fl] =
            f2us(acc[mi][ni][r] + bv[ni]);
  __syncthreads();

  // cooperative rel-add: 16 threads per tile row, 8-col chunks
  const int trow = tid >> 4;
  const int tcol = (tid & 15) * 8;
  const float w0 = wrel[0], w1 = wrel[1], w2 = wrel[2], w3 = wrel[3],
              w4 = wrel[4], w5 = wrel[5], w6 = wrel[6], w7 = wrel[7],
              w8 = wrel[8];
  const float wj[9] = {w0, w1, w2, w3, w4, w5, w6, w7, w8};
  #pragma unroll
  for (int i = 0; i < 8; ++i) {
    int r = trow + i * 16;
    int gr = bm + r;
    int b = gr >> 10, s = gr & (S_ - 1);
    float a8[8];
    unpack8(*reinterpret_cast<const uint4*>(&smem[r * 136 + tcol]), a8);
    const unsigned short* np =
        nin + ((size_t)b * S2_ + off + s) * D_ + bn + tcol;
    #pragma unroll
    for (int j = 0; j < 9; ++j) {
      float nf[8];
      unpack8(*reinterpret_cast<const uint4*>(np + (size_t)j * D_), nf);
      #pragma unroll
      for (int e = 0; e < 8; ++e) a8[e] += wj[j] * nf[e];
    }
    uint4 o;
    o.x = pack2(a8[0], a8[1]); o.y = pack2(a8[2], a8[3]);
    o.z = pack2(a8[4], a8[5]); o.w = pack2(a8[6], a8[7]);
    *reinterpret_cast<uint4*>(
        hwx + (size_t)z * MS + (size_t)gr * D_ + bn + tcol) = o;
  }
}

// ---------------------------------------------------------------------------
// Windowed attention, compacted output. Wave = (dir, b, s), i = s + WIDTH.
// qkv ld 3072: dir*1536 + {q:0,k:512,v:1024}. ctx: (2,B,S,512).
__global__ __launch_bounds__(256) void k_attn_window(
    const unsigned short* __restrict__ qkv,
    unsigned short* __restrict__ ctx)
{
  int wid = (blockIdx.x * 256 + threadIdx.x) >> 6;   // dir*B*S + b*S + s
  int lane = threadIdx.x & 63;
  int s = wid & (S_ - 1);
  int b = (wid >> 10) & (B_ - 1);
  int dir = wid >> 13;
  int i = s + WIDTH_;

  const size_t base = (size_t)b * S2_ * 3072 + dir * 1536;
  const int c0 = lane * 8;

  float qf[8];
  unpack8(*reinterpret_cast<const uint4*>(qkv + base + (size_t)i * 3072 + c0), qf);

  float sc[10];
  float mx = -1e30f;
  #pragma unroll
  for (int t = 0; t < 10; ++t) {
    int j = (dir == 0) ? (i - 9 + t) : (i + t);
    float sv = -1e30f;
    if (j >= 0 && j < S2_) {
      float kf[8];
      unpack8(*reinterpret_cast<const uint4*>(
          qkv + base + (size_t)j * 3072 + 512 + c0), kf);
      float p = qf[0] * kf[0];
      #pragma unroll
      for (int e = 1; e < 8; ++e) p += qf[e] * kf[e];
      p += __shfl_xor(p, 1);
      p += __shfl_xor(p, 2);
      p += __shfl_xor(p, 4);
      sv = p * 0.125f;
    }
    sc[t] = sv;
    mx = fmaxf(mx, sv);
  }

  float denom = 0.f;
  #pragma unroll
  for (int t = 0; t < 10; ++t) {
    sc[t] = (sc[t] > -1e29f) ? __expf(sc[t] - mx) : 0.f;
    denom += sc[t];
  }
  float inv = 1.f / denom;

  float acc[8] = {0.f, 0.f, 0.f, 0.f, 0.f, 0.f, 0.f, 0.f};
  #pragma unroll
  for (int t = 0; t < 10; ++t) {
    int j = (dir == 0) ? (i - 9 + t) : (i + t);
    if (j >= 0 && j < S2_) {
      float vf[8];
      unpack8(*reinterpret_cast<const uint4*>(
          qkv + base + (size_t)j * 3072 + 1024 + c0), vf);
      float p = sc[t];
      #pragma unroll
      for (int e = 0; e < 8; ++e) acc[e] += p * vf[e];
    }
  }

  uint4 o;
  o.x = pack2(acc[0] * inv, acc[1] * inv);
  o.y = pack2(acc[2] * inv, acc[3] * inv);
  o.z = pack2(acc[4] * inv, acc[5] * inv);
  o.w = pack2(acc[6] * inv, acc[7] * inv);
  *reinterpret_cast<uint4*>(
      ctx + (((size_t)dir * B_ + b) * S_ + s) * D_ + c0) = o;
}

// ---------------------------------------------------------------------------
extern "C" void kernel_launch(void* const* d_in, const int* in_sizes, int n_in,
                              void* d_out, int out_size, void* d_ws, size_t ws_size,
                              hipStream_t stream) {
  const float* x    = (const float*)d_in[0];
  const float* lW   = (const float*)d_in[1];
  const float* lb   = (const float*)d_in[2];
  const float* rW   = (const float*)d_in[3];
  const float* rb   = (const float*)d_in[4];
  const float* lpad = (const float*)d_in[5];
  const float* rpad = (const float*)d_in[6];
  const float* lw   = (const float*)d_in[7];
  const float* rw   = (const float*)d_in[8];
  const float* lhwW = (const float*)d_in[9];
  const float* lhwb = (const float*)d_in[10];
  const float* rhwW = (const float*)d_in[11];
  const float* rhwb = (const float*)d_in[12];
  float* out = (float*)d_out;
  unsigned short* ws = (unsigned short*)d_ws;

  const size_t NIN  = (size_t)B_ * S2_ * D_;       // 4,259,840
  const size_t NQKV = (size_t)B_ * S2_ * 3072;     // 25,559,040
  const size_t MS   = (size_t)B_ * S_ * D_;        // 4,194,304
  const size_t DD   = (size_t)D_ * D_;             // 262,144
  const size_t LHW  = (size_t)1024 * 512;          // 524,288

  unsigned short* nin   = ws;
  unsigned short* qkv   = nin + NIN;
  unsigned short* ctx   = qkv + NQKV;              // (2,B,S,D)
  unsigned short* hwx   = ctx + 2 * MS;            // (2,B,S,D)
  unsigned short* hwy   = hwx + 2 * MS;            // (2,B,S,D)
  unsigned short* WTall = hwy + 2 * MS;            // (3072,512)
  unsigned short* WTp   = WTall + 6 * DD;          // (2,512,512)
  unsigned short* hWT   = WTp + 2 * DD;            // (2,2,1024,512)
  float* qkvbias        = (float*)(hWT + 4 * LHW); // 3072 fp32

  // --- prep: 1 dispatch ---
  k_prep<<<6188, 256, 0, stream>>>(x, lpad, rpad, lW, rW, lb, rb, lhwW, rhwW,
                                   WTall, WTp, hWT, nin, qkvbias);

  const int MQ = B_ * S2_;   // 8320

  // --- fused QKV both sides: (8320 x 3072), 256^2 8-phase ---
  {
    dim3 g(3072 / 256, 33, 1);   // (12, 33); last M-tile clamps rows
    k_gemm256<0><<<g, 512, 0, stream>>>(nin, 0, WTall, 0, qkvbias, nullptr,
                                        qkv, nullptr, MQ, 3072);
  }

  // --- attention, both sides, compacted ctx ---
  k_attn_window<<<(2 * B_ * S_) / 4, 256, 0, stream>>>(qkv, ctx);

  // --- proj + fused rel-add, z-batched over side (128^2 kernel) ---
  {
    dim3 g(D_ / 128, (B_ * S_) / 128, 2);   // (4, 64, 2)
    k_gemm_proj<<<g, 256, 0, stream>>>(ctx, WTp, nin, lb + 3 * D_, rb + 3 * D_,
                                       lw, rw, hwx);
  }

  // --- highway layers: 256^2 8-phase + fused gate, z-batched over side ---
  {
    dim3 g(1024 / 256, (B_ * S_) / 256, 2);   // (4, 32, 2)
    k_gemm256<1><<<g, 512, 0, stream>>>(hwx, MS, hWT, 2 * LHW,
                                        lhwb, rhwb, hwy, nullptr,
                                        B_ * S_, 1024);
    k_gemm256<2><<<g, 512, 0, stream>>>(hwy, MS, hWT + LHW, 2 * LHW,
                                        lhwb + 1024, rhwb + 1024,
                                        nullptr, out, B_ * S_, 1024);
  }
}

// Round 2
// 237.171 us; speedup vs baseline: 1.0501x; 1.0251x over previous
//
#include <hip/hip_runtime.h>

// SelfAttentiveLBLBiLM on MI355X — round 9.
// r8 post-mortem: 256^2 8-phase schedule landed correct but SLOW — 2.84M LDS
// bank conflicts. Root cause: 1-bit swizzle ((row>>2)&1 -> bit5) only spreads
// frag reads over 4 of 8 16B slots per 128B bank row (rows are 128B; bank =
// col mod 128). Fix (G4/m214 recipe): 3-bit XOR swizzle, col ^= (row&7)<<4,
// applied BOTH sides: ds_read col gets ^((fl&7)<<4); global_load_lds source
// pre-swizzled with rr=l>>3, ce=((l&7)*16)^(rr<<4). Every aligned 8-lane
// group now covers all 8 slots -> conflict-free. Schedule/epilogues unchanged.
// Dispatches: prep, qkv gemm256, attn, proj+rel gemm(128^2), hw gemm256 x2.

#define B_ 8
#define S_ 1024
#define D_ 512
#define H_ 8
#define DK_ 64
#define WIDTH_ 8
#define S2_ 1040
#define NHW_ 2

typedef short bf16x8 __attribute__((ext_vector_type(8)));
typedef float f32x4 __attribute__((ext_vector_type(4)));

__device__ __forceinline__ float us2f(unsigned short u) {
  union { unsigned int i; float f; } c; c.i = ((unsigned int)u) << 16; return c.f;
}
__device__ __forceinline__ unsigned short f2us(float f) {
  union { float f; unsigned int i; } c; c.f = f;
  unsigned int x = c.i;
  return (unsigned short)((x + 0x7fffu + ((x >> 16) & 1u)) >> 16);
}
__device__ __forceinline__ unsigned int pack2(float a, float b) {
  return (unsigned int)f2us(a) | ((unsigned int)f2us(b) << 16);
}
__device__ __forceinline__ void async16(const void* g, void* l) {
  __builtin_amdgcn_global_load_lds(
      (const __attribute__((address_space(1))) void*)g,
      (__attribute__((address_space(3))) void*)l, 16, 0, 0);
}
__device__ __forceinline__ void unpack8(uint4 u, float* f) {
  unsigned int w[4] = {u.x, u.y, u.z, u.w};
  #pragma unroll
  for (int c = 0; c < 4; ++c) {
    union { unsigned int i; float g; } lo, hi;
    lo.i = w[c] << 16;
    hi.i = w[c] & 0xffff0000u;
    f[2 * c] = lo.g;
    f[2 * c + 1] = hi.g;
  }
}

// ---------------------------------------------------------------------------
// Prep mega-kernel. blockIdx.x ranges:
//  [0,2048): attn weight transpose, 8 slices (side=sl>>2, slice=sl&3), 16x16
//  [2048,4096): hw weight transpose+interleave (256-tile pairing), 4 slices
//  [4096,6188): build new_in (+ qkv bias tail)
__global__ __launch_bounds__(256) void k_prep(
    const float* __restrict__ x,
    const float* __restrict__ lpad, const float* __restrict__ rpad,
    const float* __restrict__ lW, const float* __restrict__ rW,
    const float* __restrict__ lb, const float* __restrict__ rb,
    const float* __restrict__ lhwW, const float* __restrict__ rhwW,
    unsigned short* __restrict__ WTall, unsigned short* __restrict__ WTp,
    unsigned short* __restrict__ hWT,
    unsigned short* __restrict__ nin, float* __restrict__ qkvbias)
{
  __shared__ float tile[32][33];
  const size_t DD = (size_t)D_ * D_;
  int bx = blockIdx.x;
  int tx = threadIdx.x & 31, ty = threadIdx.x >> 5;

  if (bx < 2048) {                     // ---- attn transpose
    int sl = bx >> 8, rem = bx & 255;
    int side = sl >> 2, slice = sl & 3;
    int c0 = (rem & 15) * 32, r0 = (rem >> 4) * 32;
    const float* src = (side ? rW : lW) + (size_t)slice * DD;
    unsigned short* dst = (slice < 3) ? WTall + (size_t)(side * 3 + slice) * DD
                                      : WTp + (size_t)side * DD;
    #pragma unroll
    for (int i = 0; i < 4; ++i)
      tile[ty + i * 8][tx] = src[(size_t)(r0 + ty + i * 8) * D_ + c0 + tx];
    __syncthreads();
    #pragma unroll
    for (int i = 0; i < 4; ++i)
      dst[(size_t)(c0 + ty + i * 8) * D_ + r0 + tx] = f2us(tile[tx][ty + i * 8]);
    return;
  }
  if (bx < 4096) {                     // ---- hw transpose + interleave
    int idx = bx - 2048;
    int sl = idx >> 9, rem = idx & 511;    // sl: side*2+layer
    int c0 = (rem & 31) * 32, r0 = (rem >> 5) * 32;
    const float* src = ((sl >> 1) ? rhwW : lhwW) + (size_t)(sl & 1) * 512 * 1024;
    unsigned short* dst = hWT + (size_t)sl * 1024 * 512;
    #pragma unroll
    for (int i = 0; i < 4; ++i)
      tile[ty + i * 8][tx] = src[(size_t)(r0 + ty + i * 8) * 1024 + c0 + tx];
    __syncthreads();
    // 256-tile pairing: orig col c (nl: c<512, g: c>=512) -> BT row q such
    // that nl x and g x land in ni=2np / 2np+1 of the same wave wn.
    #pragma unroll
    for (int i = 0; i < 4; ++i) {
      int c = c0 + ty + i * 8;
      int cm = c & 511;
      int j = cm >> 4;                       // 16-col block of x, 0..31
      int jl = j & 7;
      int Bq = ((jl >> 2) << 3) + (jl & 3) + ((c >= 512) ? 4 : 0);
      int q = (j >> 3) * 256 + Bq * 16 + (cm & 15);
      dst[(size_t)q * 512 + r0 + tx] = f2us(tile[tx][ty + i * 8]);
    }
    return;
  }
  // ---- build new_in + bias tail
  int gid = (bx - 4096) * 256 + threadIdx.x;
  const int NTH = B_ * S2_ * 64;       // 532,480
  if (gid >= NTH) {
    int t = gid - NTH;
    if (t < 1536) qkvbias[t] = lb[t];
    else if (t < 3072) qkvbias[t] = rb[t - 1536];
    return;
  }
  int c8 = (gid & 63) << 3;
  int row = gid >> 6;
  int b = row / S2_;
  int t = row - b * S2_;
  const float* src;
  if (t < WIDTH_)            src = lpad + (size_t)t * D_ + c8;
  else if (t >= S_ + WIDTH_) src = rpad + (size_t)(t - S_ - WIDTH_) * D_ + c8;
  else                       src = x + ((size_t)b * S_ + (t - WIDTH_)) * D_ + c8;
  float4 a = *reinterpret_cast<const float4*>(src);
  float4 c = *reinterpret_cast<const float4*>(src + 4);
  uint4 o;
  o.x = pack2(a.x, a.y); o.y = pack2(a.z, a.w);
  o.z = pack2(c.x, c.y); o.w = pack2(c.z, c.w);
  *reinterpret_cast<uint4*>(nin + (size_t)row * D_ + c8) = o;
}

// ---------------------------------------------------------------------------
// 256x256 8-phase GEMM, K=512. C(M,N) = A(M,K) @ BT(N,K)^T, fused epilogue:
//  EPI=0: +bias(N), bf16 store stride N (QKV)
//  EPI=1: highway gate -> bf16 (z*MS + row*512 + x)
//  EPI=2: highway gate -> f32  (row*1024 + z*512 + x)
// 8 waves = 2(M) x 4(N); per-wave 128x64 out; LDS 128 KiB:
//  A: [buf][half] 128x64 bf16 (16 KB each), B likewise at +64 KB.
// 3-bit XOR swizzle (G4/m214): col_byte ^= (row&7)<<4, applied via
// pre-swizzled global source (linear global_load_lds dest) + swizzled
// ds_read cols. Every aligned 8-lane group covers all 8 16B slots.
template <int EPI>
__global__ __launch_bounds__(512, 2) void k_gemm256(
    const unsigned short* __restrict__ Abase, size_t aStrZ,
    const unsigned short* __restrict__ BTbase, size_t bStrZ,
    const float* __restrict__ bias0, const float* __restrict__ bias1,
    unsigned short* __restrict__ Cbf, float* __restrict__ Cfp,
    int M, int N)
{
  __shared__ __align__(16) unsigned short smem[65536];   // 128 KiB
  const int tid = threadIdx.x;
  const int w = tid >> 6, l = tid & 63;
  const int wm = w >> 2, wn = w & 3;
  const int fl = l & 15, fq = l >> 4;
  const int z = blockIdx.z;
  const unsigned short* A = Abase + (size_t)z * aStrZ;
  const unsigned short* BT = BTbase + (size_t)z * bStrZ;
  const int bm = blockIdx.y * 256, bn = blockIdx.x * 256;

  // frag-read constants (short offsets). Logical col byte c = s*64 + fq*16,
  // row&7 = fl&7 -> read at c ^ ((fl&7)<<4).
  const int xorb = (fl & 7) << 4;
  const int cs0 = ((fq * 16) ^ xorb) >> 1;        // k-slice 0
  const int cs1 = ((64 + fq * 16) ^ xorb) >> 1;   // k-slice 1

  // stage-source constants: lane l writes LDS (row rr = l>>3 in its 8-row
  // chunk, col byte (l&7)*16); source element = logical col ^ (rr<<4).
  const int rr = l >> 3;
  const int ce = (((l & 7) * 16) ^ (rr << 4)) >> 1;   // shorts
  const unsigned short* gA[2][2];
  const unsigned short* gB[2][2];
  #pragma unroll
  for (int i = 0; i < 2; ++i)
    #pragma unroll
    for (int h = 0; h < 2; ++h) {
      int ra = bm + h * 128 + (2 * w + i) * 8 + rr;
      if (ra > M - 1) ra = M - 1;            // M=8320 tail clamp (QKV)
      gA[i][h] = A + (size_t)ra * 512 + ce;
      int rb = bn + h * 128 + (2 * w + i) * 8 + rr;
      gB[i][h] = BT + (size_t)rb * 512 + ce;
    }

  f32x4 acc[8][4];
  #pragma unroll
  for (int mi = 0; mi < 8; ++mi)
    #pragma unroll
    for (int ni = 0; ni < 4; ++ni) acc[mi][ni] = (f32x4){0.f, 0.f, 0.f, 0.f};

  bf16x8 ar[4][2], br[2][2];

#define BAR() __builtin_amdgcn_s_barrier()
#define STGA(buf, h, kt) do { \
    async16(gA[0][h] + (kt) * 64, &smem[((buf) * 2 + (h)) * 8192 + (2 * w) * 512]); \
    async16(gA[1][h] + (kt) * 64, &smem[((buf) * 2 + (h)) * 8192 + (2 * w + 1) * 512]); } while (0)
#define STGB(buf, h, kt) do { \
    async16(gB[0][h] + (kt) * 64, &smem[32768 + ((buf) * 2 + (h)) * 8192 + (2 * w) * 512]); \
    async16(gB[1][h] + (kt) * 64, &smem[32768 + ((buf) * 2 + (h)) * 8192 + (2 * w + 1) * 512]); } while (0)
#define LDA(buf, h) do { const unsigned short* p_ = &smem[((buf) * 2 + (h)) * 8192]; \
    _Pragma("unroll") for (int m4 = 0; m4 < 4; ++m4) { \
      int ro_ = ((2 * m4 + wm) * 16 + fl) * 64; \
      ar[m4][0] = *reinterpret_cast<const bf16x8*>(p_ + ro_ + cs0); \
      ar[m4][1] = *reinterpret_cast<const bf16x8*>(p_ + ro_ + cs1); } } while (0)
#define LDB(buf, h) do { const unsigned short* p_ = &smem[32768 + ((buf) * 2 + (h)) * 8192]; \
    _Pragma("unroll") for (int n2 = 0; n2 < 2; ++n2) { \
      int ro_ = ((4 * n2 + wn) * 16 + fl) * 64; \
      br[n2][0] = *reinterpret_cast<const bf16x8*>(p_ + ro_ + cs0); \
      br[n2][1] = *reinterpret_cast<const bf16x8*>(p_ + ro_ + cs1); } } while (0)
#define QUAD(miH, niH) do { __builtin_amdgcn_s_setprio(1); \
    _Pragma("unroll") for (int m4 = 0; m4 < 4; ++m4) \
      _Pragma("unroll") for (int n2 = 0; n2 < 2; ++n2) \
        _Pragma("unroll") for (int s_ = 0; s_ < 2; ++s_) \
          acc[(miH) * 4 + m4][(niH) * 2 + n2] = __builtin_amdgcn_mfma_f32_16x16x32_bf16( \
              ar[m4][s_], br[n2][s_], acc[(miH) * 4 + m4][(niH) * 2 + n2], 0, 0, 0); \
    __builtin_amdgcn_s_setprio(0); } while (0)

  // prologue: T0 {A0,B0,B1,A1} -> buf0, T1 {A0,B1,A1} -> buf1 (B0 at I1).
  STGA(0, 0, 0); STGB(0, 0, 0); STGB(0, 1, 0); STGA(0, 1, 0);
  STGA(1, 0, 1); STGB(1, 1, 1); STGA(1, 1, 1);
  asm volatile("s_waitcnt vmcnt(6)" ::: "memory");   // T0 fully landed
  BAR();

  #pragma unroll 1
  for (int it = 0; it < 4; ++it) {
    const int t1 = 2 * it + 1, t2 = 2 * it + 2, t3 = 2 * it + 3;
    // ph1: quad(0,0) buf0 | I1: t1.B0 -> buf1.B0 (last read prev ph8)
    LDA(0, 0); LDB(0, 0);
    STGB(1, 0, t1);
    BAR(); QUAD(0, 0); BAR();
    // ph2: quad(0,1) buf0 | I2: t2.A0 -> buf0.A0 (last read ph1)
    LDB(0, 1);
    if (t2 < 8) STGA(0, 0, t2);
    BAR(); QUAD(0, 1); BAR();
    // ph3: quad(1,1) buf0 | I3: t2.B1 -> buf0.B1 (last read ph2)
    LDA(0, 1);
    if (t2 < 8) STGB(0, 1, t2);
    BAR(); QUAD(1, 1); BAR();
    // ph4: quad(1,0) buf0 | I4: t2.A1 -> buf0.A1 (last read ph3)
    LDB(0, 0);
    if (t2 < 8) STGA(0, 1, t2);
    BAR(); QUAD(1, 0);
    if (it < 3) asm volatile("s_waitcnt vmcnt(6)" ::: "memory");
    else        asm volatile("s_waitcnt vmcnt(0)" ::: "memory");
    BAR();
    // ph5: quad(0,0) buf1 | I5: t2.B0 -> buf0.B0 (last read ph4)
    LDA(1, 0); LDB(1, 0);
    if (t2 < 8) STGB(0, 0, t2);
    BAR(); QUAD(0, 0); BAR();
    // ph6: quad(0,1) buf1 | I6: t3.A0 -> buf1.A0 (last read ph5)
    LDB(1, 1);
    if (t3 < 8) STGA(1, 0, t3);
    BAR(); QUAD(0, 1); BAR();
    // ph7: quad(1,1) buf1 | I7: t3.B1 -> buf1.B1 (last read ph6)
    LDA(1, 1);
    if (t3 < 8) STGB(1, 1, t3);
    BAR(); QUAD(1, 1); BAR();
    // ph8: quad(1,0) buf1 | I8: t3.A1 -> buf1.A1 (last read ph7)
    LDB(1, 0);
    if (t3 < 8) STGA(1, 1, t3);
    BAR(); QUAD(1, 0);
    asm volatile("s_waitcnt vmcnt(6)" ::: "memory");
    BAR();
  }
#undef BAR
#undef STGA
#undef STGB
#undef LDA
#undef LDB
#undef QUAD

  // ---- epilogue
  if (EPI == 0) {
    float bv[4];
    #pragma unroll
    for (int ni = 0; ni < 4; ++ni) bv[ni] = bias0[bn + (4 * ni + wn) * 16 + fl];
    #pragma unroll
    for (int mi = 0; mi < 8; ++mi) {
      #pragma unroll
      for (int r = 0; r < 4; ++r) {
        int gr = bm + (2 * mi + wm) * 16 + fq * 4 + r;
        if (gr < M) {
          unsigned short* Cp = Cbf + (size_t)gr * N + bn + wn * 16 + fl;
          #pragma unroll
          for (int ni = 0; ni < 4; ++ni) Cp[ni * 64] = f2us(acc[mi][ni][r] + bv[ni]);
        }
      }
    }
  } else {
    const float* bias = z ? bias1 : bias0;
    const size_t MS = (size_t)B_ * S_ * D_;
    float bnl[2], bg[2]; int xs[2];
    #pragma unroll
    for (int np = 0; np < 2; ++np) {
      xs[np] = (blockIdx.x * 8 + np * 4 + wn) * 16 + fl;
      bnl[np] = bias[xs[np]];
      bg[np]  = bias[512 + xs[np]];
    }
    #pragma unroll
    for (int mi = 0; mi < 8; ++mi) {
      #pragma unroll
      for (int r = 0; r < 4; ++r) {
        int gr = bm + (2 * mi + wm) * 16 + fq * 4 + r;
        #pragma unroll
        for (int np = 0; np < 2; ++np) {
          float nl = fmaxf(acc[mi][2 * np][r] + bnl[np], 0.f);
          float g  = 1.f / (1.f + __expf(-(acc[mi][2 * np + 1][r] + bg[np])));
          float xv = us2f(A[(size_t)gr * 512 + xs[np]]);
          float res = g * xv + (1.f - g) * nl;
          if (EPI == 2) Cfp[(size_t)gr * 1024 + (size_t)z * 512 + xs[np]] = res;
          else Cbf[(size_t)z * MS + (size_t)gr * 512 + xs[np]] = f2us(res);
        }
      }
    }
  }
}

// ---------------------------------------------------------------------------
// Proj GEMM + fused rel-add (unchanged 128^2 structure; N=512 packs badly at
// 256^2). A = ctx (2,8192,512) bf16 compacted; z = side.
__global__ __launch_bounds__(256) void k_gemm_proj(
    const unsigned short* __restrict__ ctx,
    const unsigned short* __restrict__ WTp,    // (2,512,512)
    const unsigned short* __restrict__ nin,    // (B,S2,512)
    const float* __restrict__ lb3, const float* __restrict__ rb3,
    const float* __restrict__ wrel0, const float* __restrict__ wrel1,
    unsigned short* __restrict__ hwx)          // (2,8192,512)
{
  __shared__ unsigned short smem[128 * 136];   // 34.8 KB; staging uses 32 KB
  unsigned short* As = smem;
  unsigned short* Bs = smem + 8192;
  const int K = 512, N = 512;
  const size_t MS = (size_t)B_ * S_ * D_;

  const int z = blockIdx.z;
  const unsigned short* A = ctx + (size_t)z * MS;
  const unsigned short* BT = WTp + (size_t)z * 512 * 512;
  const float* bias = z ? rb3 : lb3;
  const float* wrel = z ? wrel1 : wrel0;
  const int off = z * WIDTH_;

  const int tid = threadIdx.x;
  const int w = tid >> 6;
  const int l = tid & 63;
  const int bm = blockIdx.y * 128;
  const int bn = blockIdx.x * 128;
  const int wrow = (w >> 1) * 64;
  const int wcol = (w & 1) * 64;

  const int lr = l >> 3;
  const int sk = (((l & 7) ^ lr) & 7) * 8;
  const unsigned short* Ap = A + (size_t)(bm + w * 8 + lr) * K + sk;
  const unsigned short* Bp = BT + (size_t)(bn + w * 8 + lr) * K + sk;
  unsigned short* lA = &As[w * 512];
  unsigned short* lB = &Bs[w * 512];
  const size_t K32 = (size_t)32 * K;

  const int fl = l & 15;
  const int fq = l >> 4;
  const int fx = fl & 7;

  f32x4 acc[4][4];
  #pragma unroll
  for (int mi = 0; mi < 4; ++mi)
    #pragma unroll
    for (int ni = 0; ni < 4; ++ni) acc[mi][ni] = (f32x4){0.f, 0.f, 0.f, 0.f};

  for (int k0 = 0; k0 < K; k0 += 64) {
    #pragma unroll
    for (int r = 0; r < 4; ++r) {
      async16(Ap + k0 + r * K32, lA + r * 2048);
      async16(Bp + k0 + r * K32, lB + r * 2048);
    }
    __syncthreads();
    #pragma unroll
    for (int s = 0; s < 2; ++s) {
      bf16x8 af[4], bfr[4];
      #pragma unroll
      for (int mi = 0; mi < 4; ++mi)
        af[mi] = *reinterpret_cast<const bf16x8*>(
            &As[(wrow + mi * 16 + fl) * 64 + (((s * 4 + fq) ^ fx) * 8)]);
      #pragma unroll
      for (int ni = 0; ni < 4; ++ni)
        bfr[ni] = *reinterpret_cast<const bf16x8*>(
            &Bs[(wcol + ni * 16 + fl) * 64 + (((s * 4 + fq) ^ fx) * 8)]);
      #pragma unroll
      for (int mi = 0; mi < 4; ++mi)
        #pragma unroll
        for (int ni = 0; ni < 4; ++ni)
          acc[mi][ni] = __builtin_amdgcn_mfma_f32_16x16x32_bf16(
              af[mi], bfr[ni], acc[mi][ni], 0, 0, 0);
    }
    __syncthreads();
  }

  // stage bias-added tile into LDS (bf16, ld 136)
  float bv[4];
  #pragma unroll
  for (int ni = 0; ni < 4; ++ni) bv[ni] = bias[bn + wcol + ni * 16 + fl];
  const int rbase = (l >> 4) * 4;
  #pragma unroll
  for (int mi = 0; mi < 4; ++mi)
    #pragma unroll
    for (int r = 0; r < 4; ++r)
      #pragma unroll
      for (int ni = 0; ni < 4; ++ni)
        smem[(wrow + mi * 16 + rbase + r) * 136 + wcol + ni * 16 + fl] =
            f2us(acc[mi][ni][r] + bv[ni]);
  __syncthreads();

  // cooperative rel-add: 16 threads per tile row, 8-col chunks
  const int trow = tid >> 4;
  const int tcol = (tid & 15) * 8;
  const float w0 = wrel[0], w1 = wrel[1], w2 = wrel[2], w3 = wrel[3],
              w4 = wrel[4], w5 = wrel[5], w6 = wrel[6], w7 = wrel[7],
              w8 = wrel[8];
  const float wj[9] = {w0, w1, w2, w3, w4, w5, w6, w7, w8};
  #pragma unroll
  for (int i = 0; i < 8; ++i) {
    int r = trow + i * 16;
    int gr = bm + r;
    int b = gr >> 10, s = gr & (S_ - 1);
    float a8[8];
    unpack8(*reinterpret_cast<const uint4*>(&smem[r * 136 + tcol]), a8);
    const unsigned short* np =
        nin + ((size_t)b * S2_ + off + s) * D_ + bn + tcol;
    #pragma unroll
    for (int j = 0; j < 9; ++j) {
      float nf[8];
      unpack8(*reinterpret_cast<const uint4*>(np + (size_t)j * D_), nf);
      #pragma unroll
      for (int e = 0; e < 8; ++e) a8[e] += wj[j] * nf[e];
    }
    uint4 o;
    o.x = pack2(a8[0], a8[1]); o.y = pack2(a8[2], a8[3]);
    o.z = pack2(a8[4], a8[5]); o.w = pack2(a8[6], a8[7]);
    *reinterpret_cast<uint4*>(
        hwx + (size_t)z * MS + (size_t)gr * D_ + bn + tcol) = o;
  }
}

// ---------------------------------------------------------------------------
// Windowed attention, compacted output. Wave = (dir, b, s), i = s + WIDTH.
// qkv ld 3072: dir*1536 + {q:0,k:512,v:1024}. ctx: (2,B,S,512).
__global__ __launch_bounds__(256) void k_attn_window(
    const unsigned short* __restrict__ qkv,
    unsigned short* __restrict__ ctx)
{
  int wid = (blockIdx.x * 256 + threadIdx.x) >> 6;   // dir*B*S + b*S + s
  int lane = threadIdx.x & 63;
  int s = wid & (S_ - 1);
  int b = (wid >> 10) & (B_ - 1);
  int dir = wid >> 13;
  int i = s + WIDTH_;

  const size_t base = (size_t)b * S2_ * 3072 + dir * 1536;
  const int c0 = lane * 8;

  float qf[8];
  unpack8(*reinterpret_cast<const uint4*>(qkv + base + (size_t)i * 3072 + c0), qf);

  float sc[10];
  float mx = -1e30f;
  #pragma unroll
  for (int t = 0; t < 10; ++t) {
    int j = (dir == 0) ? (i - 9 + t) : (i + t);
    float sv = -1e30f;
    if (j >= 0 && j < S2_) {
      float kf[8];
      unpack8(*reinterpret_cast<const uint4*>(
          qkv + base + (size_t)j * 3072 + 512 + c0), kf);
      float p = qf[0] * kf[0];
      #pragma unroll
      for (int e = 1; e < 8; ++e) p += qf[e] * kf[e];
      p += __shfl_xor(p, 1);
      p += __shfl_xor(p, 2);
      p += __shfl_xor(p, 4);
      sv = p * 0.125f;
    }
    sc[t] = sv;
    mx = fmaxf(mx, sv);
  }

  float denom = 0.f;
  #pragma unroll
  for (int t = 0; t < 10; ++t) {
    sc[t] = (sc[t] > -1e29f) ? __expf(sc[t] - mx) : 0.f;
    denom += sc[t];
  }
  float inv = 1.f / denom;

  float acc[8] = {0.f, 0.f, 0.f, 0.f, 0.f, 0.f, 0.f, 0.f};
  #pragma unroll
  for (int t = 0; t < 10; ++t) {
    int j = (dir == 0) ? (i - 9 + t) : (i + t);
    if (j >= 0 && j < S2_) {
      float vf[8];
      unpack8(*reinterpret_cast<const uint4*>(
          qkv + base + (size_t)j * 3072 + 1024 + c0), vf);
      float p = sc[t];
      #pragma unroll
      for (int e = 0; e < 8; ++e) acc[e] += p * vf[e];
    }
  }

  uint4 o;
  o.x = pack2(acc[0] * inv, acc[1] * inv);
  o.y = pack2(acc[2] * inv, acc[3] * inv);
  o.z = pack2(acc[4] * inv, acc[5] * inv);
  o.w = pack2(acc[6] * inv, acc[7] * inv);
  *reinterpret_cast<uint4*>(
      ctx + (((size_t)dir * B_ + b) * S_ + s) * D_ + c0) = o;
}

// ---------------------------------------------------------------------------
extern "C" void kernel_launch(void* const* d_in, const int* in_sizes, int n_in,
                              void* d_out, int out_size, void* d_ws, size_t ws_size,
                              hipStream_t stream) {
  const float* x    = (const float*)d_in[0];
  const float* lW   = (const float*)d_in[1];
  const float* lb   = (const float*)d_in[2];
  const float* rW   = (const float*)d_in[3];
  const float* rb   = (const float*)d_in[4];
  const float* lpad = (const float*)d_in[5];
  const float* rpad = (const float*)d_in[6];
  const float* lw   = (const float*)d_in[7];
  const float* rw   = (const float*)d_in[8];
  const float* lhwW = (const float*)d_in[9];
  const float* lhwb = (const float*)d_in[10];
  const float* rhwW = (const float*)d_in[11];
  const float* rhwb = (const float*)d_in[12];
  float* out = (float*)d_out;
  unsigned short* ws = (unsigned short*)d_ws;

  const size_t NIN  = (size_t)B_ * S2_ * D_;       // 4,259,840
  const size_t NQKV = (size_t)B_ * S2_ * 3072;     // 25,559,040
  const size_t MS   = (size_t)B_ * S_ * D_;        // 4,194,304
  const size_t DD   = (size_t)D_ * D_;             // 262,144
  const size_t LHW  = (size_t)1024 * 512;          // 524,288

  unsigned short* nin   = ws;
  unsigned short* qkv   = nin + NIN;
  unsigned short* ctx   = qkv + NQKV;              // (2,B,S,D)
  unsigned short* hwx   = ctx + 2 * MS;            // (2,B,S,D)
  unsigned short* hwy   = hwx + 2 * MS;            // (2,B,S,D)
  unsigned short* WTall = hwy + 2 * MS;            // (3072,512)
  unsigned short* WTp   = WTall + 6 * DD;          // (2,512,512)
  unsigned short* hWT   = WTp + 2 * DD;            // (2,2,1024,512)
  float* qkvbias        = (float*)(hWT + 4 * LHW); // 3072 fp32

  // --- prep: 1 dispatch ---
  k_prep<<<6188, 256, 0, stream>>>(x, lpad, rpad, lW, rW, lb, rb, lhwW, rhwW,
                                   WTall, WTp, hWT, nin, qkvbias);

  const int MQ = B_ * S2_;   // 8320

  // --- fused QKV both sides: (8320 x 3072), 256^2 8-phase ---
  {
    dim3 g(3072 / 256, 33, 1);   // (12, 33); last M-tile clamps rows
    k_gemm256<0><<<g, 512, 0, stream>>>(nin, 0, WTall, 0, qkvbias, nullptr,
                                        qkv, nullptr, MQ, 3072);
  }

  // --- attention, both sides, compacted ctx ---
  k_attn_window<<<(2 * B_ * S_) / 4, 256, 0, stream>>>(qkv, ctx);

  // --- proj + fused rel-add, z-batched over side (128^2 kernel) ---
  {
    dim3 g(D_ / 128, (B_ * S_) / 128, 2);   // (4, 64, 2)
    k_gemm_proj<<<g, 256, 0, stream>>>(ctx, WTp, nin, lb + 3 * D_, rb + 3 * D_,
                                       lw, rw, hwx);
  }

  // --- highway layers: 256^2 8-phase + fused gate, z-batched over side ---
  {
    dim3 g(1024 / 256, (B_ * S_) / 256, 2);   // (4, 32, 2)
    k_gemm256<1><<<g, 512, 0, stream>>>(hwx, MS, hWT, 2 * LHW,
                                        lhwb, rhwb, hwy, nullptr,
                                        B_ * S_, 1024);
    k_gemm256<2><<<g, 512, 0, stream>>>(hwy, MS, hWT + LHW, 2 * LHW,
                                        lhwb + 1024, rhwb + 1024,
                                        nullptr, out, B_ * S_, 1024);
  }
}

// Round 3
// 235.423 us; speedup vs baseline: 1.0579x; 1.0074x over previous
//
#include <hip/hip_runtime.h>

// SelfAttentiveLBLBiLM on MI355X — round 10.
// r9 post-mortem: swizzle fix verified (conflicts 2.84M -> 0) but 256^2
// 8-phase QKV is stall-bound at 49.7us — WORSE than r7's 128^2 2-phase
// (43.8us). Cause: K=512 -> only 4 pipeline iterations (prologue/drain not
// amortized), grid 396 @ 1 block/CU -> 23% tail, no co-resident blocks to
// hide vmcnt waits. The 128^2 kernel's ~3-5 blocks/CU wave-overlap (m114)
// wins in this regime. hw GEMMs (grid exactly 256, zero tail) DID gain from
// 256^2+swizzle (r8/r9 deltas), keep them.
// This round: QKV reverted to 128^2 2-phase; hw stays 256^2 8-phase.
// Dispatches: prep, qkv gemm(128^2), attn, proj+rel gemm(128^2), hw 256^2 x2.

#define B_ 8
#define S_ 1024
#define D_ 512
#define H_ 8
#define DK_ 64
#define WIDTH_ 8
#define S2_ 1040
#define NHW_ 2

typedef short bf16x8 __attribute__((ext_vector_type(8)));
typedef float f32x4 __attribute__((ext_vector_type(4)));

__device__ __forceinline__ float us2f(unsigned short u) {
  union { unsigned int i; float f; } c; c.i = ((unsigned int)u) << 16; return c.f;
}
__device__ __forceinline__ unsigned short f2us(float f) {
  union { float f; unsigned int i; } c; c.f = f;
  unsigned int x = c.i;
  return (unsigned short)((x + 0x7fffu + ((x >> 16) & 1u)) >> 16);
}
__device__ __forceinline__ unsigned int pack2(float a, float b) {
  return (unsigned int)f2us(a) | ((unsigned int)f2us(b) << 16);
}
__device__ __forceinline__ void async16(const void* g, void* l) {
  __builtin_amdgcn_global_load_lds(
      (const __attribute__((address_space(1))) void*)g,
      (__attribute__((address_space(3))) void*)l, 16, 0, 0);
}
__device__ __forceinline__ void unpack8(uint4 u, float* f) {
  unsigned int w[4] = {u.x, u.y, u.z, u.w};
  #pragma unroll
  for (int c = 0; c < 4; ++c) {
    union { unsigned int i; float g; } lo, hi;
    lo.i = w[c] << 16;
    hi.i = w[c] & 0xffff0000u;
    f[2 * c] = lo.g;
    f[2 * c + 1] = hi.g;
  }
}

// ---------------------------------------------------------------------------
// Prep mega-kernel. blockIdx.x ranges:
//  [0,2048): attn weight transpose, 8 slices (side=sl>>2, slice=sl&3), 16x16
//  [2048,4096): hw transpose+interleave (256-tile pairing), 4 slices
//  [4096,6188): build new_in (+ qkv bias tail)
__global__ __launch_bounds__(256) void k_prep(
    const float* __restrict__ x,
    const float* __restrict__ lpad, const float* __restrict__ rpad,
    const float* __restrict__ lW, const float* __restrict__ rW,
    const float* __restrict__ lb, const float* __restrict__ rb,
    const float* __restrict__ lhwW, const float* __restrict__ rhwW,
    unsigned short* __restrict__ WTall, unsigned short* __restrict__ WTp,
    unsigned short* __restrict__ hWT,
    unsigned short* __restrict__ nin, float* __restrict__ qkvbias)
{
  __shared__ float tile[32][33];
  const size_t DD = (size_t)D_ * D_;
  int bx = blockIdx.x;
  int tx = threadIdx.x & 31, ty = threadIdx.x >> 5;

  if (bx < 2048) {                     // ---- attn transpose
    int sl = bx >> 8, rem = bx & 255;
    int side = sl >> 2, slice = sl & 3;
    int c0 = (rem & 15) * 32, r0 = (rem >> 4) * 32;
    const float* src = (side ? rW : lW) + (size_t)slice * DD;
    unsigned short* dst = (slice < 3) ? WTall + (size_t)(side * 3 + slice) * DD
                                      : WTp + (size_t)side * DD;
    #pragma unroll
    for (int i = 0; i < 4; ++i)
      tile[ty + i * 8][tx] = src[(size_t)(r0 + ty + i * 8) * D_ + c0 + tx];
    __syncthreads();
    #pragma unroll
    for (int i = 0; i < 4; ++i)
      dst[(size_t)(c0 + ty + i * 8) * D_ + r0 + tx] = f2us(tile[tx][ty + i * 8]);
    return;
  }
  if (bx < 4096) {                     // ---- hw transpose + interleave
    int idx = bx - 2048;
    int sl = idx >> 9, rem = idx & 511;    // sl: side*2+layer
    int c0 = (rem & 31) * 32, r0 = (rem >> 5) * 32;
    const float* src = ((sl >> 1) ? rhwW : lhwW) + (size_t)(sl & 1) * 512 * 1024;
    unsigned short* dst = hWT + (size_t)sl * 1024 * 512;
    #pragma unroll
    for (int i = 0; i < 4; ++i)
      tile[ty + i * 8][tx] = src[(size_t)(r0 + ty + i * 8) * 1024 + c0 + tx];
    __syncthreads();
    // 256-tile pairing: orig col c (nl: c<512, g: c>=512) -> BT row q such
    // that nl x and g x land in ni=2np / 2np+1 of the same wave wn.
    #pragma unroll
    for (int i = 0; i < 4; ++i) {
      int c = c0 + ty + i * 8;
      int cm = c & 511;
      int j = cm >> 4;                       // 16-col block of x, 0..31
      int jl = j & 7;
      int Bq = ((jl >> 2) << 3) + (jl & 3) + ((c >= 512) ? 4 : 0);
      int q = (j >> 3) * 256 + Bq * 16 + (cm & 15);
      dst[(size_t)q * 512 + r0 + tx] = f2us(tile[tx][ty + i * 8]);
    }
    return;
  }
  // ---- build new_in + bias tail
  int gid = (bx - 4096) * 256 + threadIdx.x;
  const int NTH = B_ * S2_ * 64;       // 532,480
  if (gid >= NTH) {
    int t = gid - NTH;
    if (t < 1536) qkvbias[t] = lb[t];
    else if (t < 3072) qkvbias[t] = rb[t - 1536];
    return;
  }
  int c8 = (gid & 63) << 3;
  int row = gid >> 6;
  int b = row / S2_;
  int t = row - b * S2_;
  const float* src;
  if (t < WIDTH_)            src = lpad + (size_t)t * D_ + c8;
  else if (t >= S_ + WIDTH_) src = rpad + (size_t)(t - S_ - WIDTH_) * D_ + c8;
  else                       src = x + ((size_t)b * S_ + (t - WIDTH_)) * D_ + c8;
  float4 a = *reinterpret_cast<const float4*>(src);
  float4 c = *reinterpret_cast<const float4*>(src + 4);
  uint4 o;
  o.x = pack2(a.x, a.y); o.y = pack2(a.z, a.w);
  o.z = pack2(c.x, c.y); o.w = pack2(c.z, c.w);
  *reinterpret_cast<uint4*>(nin + (size_t)row * D_ + c8) = o;
}

// ---------------------------------------------------------------------------
// MFMA GEMM (QKV): C(M,N) = A(M,K) @ BT(N,K)^T + bias(N).
// BK=64, XOR-swizzled LDS, tile 128x128, 4 waves. (r7 structure: the ~3-5
// blocks/CU wave-overlap beats the 8-phase pipeline at K=512.)
__global__ __launch_bounds__(256) void k_gemm_mfma(
    const unsigned short* __restrict__ A,
    const unsigned short* __restrict__ BT,
    const float* __restrict__ bias,
    unsigned short* __restrict__ C,
    int M, int N, int K)
{
  __shared__ unsigned short As[128 * 64];
  __shared__ unsigned short Bs[128 * 64];

  const int tid = threadIdx.x;
  const int w = tid >> 6;
  const int l = tid & 63;
  const int bm = blockIdx.y * 128;
  const int bn = blockIdx.x * 128;
  const int wrow = (w >> 1) * 64;
  const int wcol = (w & 1) * 64;

  const int lr = l >> 3;
  const int sk = (((l & 7) ^ lr) & 7) * 8;
  const unsigned short* Ap = A + (size_t)(bm + w * 8 + lr) * K + sk;
  const unsigned short* Bp = BT + (size_t)(bn + w * 8 + lr) * K + sk;
  unsigned short* lA = &As[w * 512];
  unsigned short* lB = &Bs[w * 512];
  const size_t K32 = (size_t)32 * K;

  const int fl = l & 15;
  const int fq = l >> 4;
  const int fx = fl & 7;

  f32x4 acc[4][4];
  #pragma unroll
  for (int mi = 0; mi < 4; ++mi)
    #pragma unroll
    for (int ni = 0; ni < 4; ++ni) acc[mi][ni] = (f32x4){0.f, 0.f, 0.f, 0.f};

  for (int k0 = 0; k0 < K; k0 += 64) {
    #pragma unroll
    for (int r = 0; r < 4; ++r) {
      async16(Ap + k0 + r * K32, lA + r * 2048);
      async16(Bp + k0 + r * K32, lB + r * 2048);
    }
    __syncthreads();
    #pragma unroll
    for (int s = 0; s < 2; ++s) {
      bf16x8 af[4], bfr[4];
      #pragma unroll
      for (int mi = 0; mi < 4; ++mi)
        af[mi] = *reinterpret_cast<const bf16x8*>(
            &As[(wrow + mi * 16 + fl) * 64 + (((s * 4 + fq) ^ fx) * 8)]);
      #pragma unroll
      for (int ni = 0; ni < 4; ++ni)
        bfr[ni] = *reinterpret_cast<const bf16x8*>(
            &Bs[(wcol + ni * 16 + fl) * 64 + (((s * 4 + fq) ^ fx) * 8)]);
      #pragma unroll
      for (int mi = 0; mi < 4; ++mi)
        #pragma unroll
        for (int ni = 0; ni < 4; ++ni)
          acc[mi][ni] = __builtin_amdgcn_mfma_f32_16x16x32_bf16(
              af[mi], bfr[ni], acc[mi][ni], 0, 0, 0);
    }
    __syncthreads();
  }

  float bv[4];
  #pragma unroll
  for (int ni = 0; ni < 4; ++ni) bv[ni] = bias[bn + wcol + ni * 16 + fl];

  const int rbase = (l >> 4) * 4;
  #pragma unroll
  for (int mi = 0; mi < 4; ++mi) {
    #pragma unroll
    for (int r = 0; r < 4; ++r) {
      int row = bm + wrow + mi * 16 + rbase + r;
      unsigned short* Cp = C + (size_t)row * N + bn + wcol + fl;
      #pragma unroll
      for (int ni = 0; ni < 4; ++ni)
        Cp[ni * 16] = f2us(acc[mi][ni][r] + bv[ni]);
    }
  }
}

// ---------------------------------------------------------------------------
// 256x256 8-phase GEMM, K=512 (hw layers only: grid exactly 256 blocks).
//  EPI=1: highway gate -> bf16 (z*MS + row*512 + x)
//  EPI=2: highway gate -> f32  (row*1024 + z*512 + x)
// 8 waves = 2(M) x 4(N); per-wave 128x64 out; LDS 128 KiB.
// 3-bit XOR swizzle (G4/m214): col_byte ^= (row&7)<<4, both sides.
template <int EPI>
__global__ __launch_bounds__(512, 2) void k_gemm256(
    const unsigned short* __restrict__ Abase, size_t aStrZ,
    const unsigned short* __restrict__ BTbase, size_t bStrZ,
    const float* __restrict__ bias0, const float* __restrict__ bias1,
    unsigned short* __restrict__ Cbf, float* __restrict__ Cfp,
    int M, int N)
{
  __shared__ __align__(16) unsigned short smem[65536];   // 128 KiB
  const int tid = threadIdx.x;
  const int w = tid >> 6, l = tid & 63;
  const int wm = w >> 2, wn = w & 3;
  const int fl = l & 15, fq = l >> 4;
  const int z = blockIdx.z;
  const unsigned short* A = Abase + (size_t)z * aStrZ;
  const unsigned short* BT = BTbase + (size_t)z * bStrZ;
  const int bm = blockIdx.y * 256, bn = blockIdx.x * 256;

  // frag-read constants: logical col byte c = s*64 + fq*16, row&7 = fl&7
  // -> read at c ^ ((fl&7)<<4).
  const int xorb = (fl & 7) << 4;
  const int cs0 = ((fq * 16) ^ xorb) >> 1;        // k-slice 0
  const int cs1 = ((64 + fq * 16) ^ xorb) >> 1;   // k-slice 1

  // stage-source constants: lane l writes LDS (row rr = l>>3 in its 8-row
  // chunk, col byte (l&7)*16); source element = logical col ^ (rr<<4).
  const int rr = l >> 3;
  const int ce = (((l & 7) * 16) ^ (rr << 4)) >> 1;   // shorts
  const unsigned short* gA[2][2];
  const unsigned short* gB[2][2];
  #pragma unroll
  for (int i = 0; i < 2; ++i)
    #pragma unroll
    for (int h = 0; h < 2; ++h) {
      int ra = bm + h * 128 + (2 * w + i) * 8 + rr;
      if (ra > M - 1) ra = M - 1;
      gA[i][h] = A + (size_t)ra * 512 + ce;
      int rb = bn + h * 128 + (2 * w + i) * 8 + rr;
      gB[i][h] = BT + (size_t)rb * 512 + ce;
    }

  f32x4 acc[8][4];
  #pragma unroll
  for (int mi = 0; mi < 8; ++mi)
    #pragma unroll
    for (int ni = 0; ni < 4; ++ni) acc[mi][ni] = (f32x4){0.f, 0.f, 0.f, 0.f};

  bf16x8 ar[4][2], br[2][2];

#define BAR() __builtin_amdgcn_s_barrier()
#define STGA(buf, h, kt) do { \
    async16(gA[0][h] + (kt) * 64, &smem[((buf) * 2 + (h)) * 8192 + (2 * w) * 512]); \
    async16(gA[1][h] + (kt) * 64, &smem[((buf) * 2 + (h)) * 8192 + (2 * w + 1) * 512]); } while (0)
#define STGB(buf, h, kt) do { \
    async16(gB[0][h] + (kt) * 64, &smem[32768 + ((buf) * 2 + (h)) * 8192 + (2 * w) * 512]); \
    async16(gB[1][h] + (kt) * 64, &smem[32768 + ((buf) * 2 + (h)) * 8192 + (2 * w + 1) * 512]); } while (0)
#define LDA(buf, h) do { const unsigned short* p_ = &smem[((buf) * 2 + (h)) * 8192]; \
    _Pragma("unroll") for (int m4 = 0; m4 < 4; ++m4) { \
      int ro_ = ((2 * m4 + wm) * 16 + fl) * 64; \
      ar[m4][0] = *reinterpret_cast<const bf16x8*>(p_ + ro_ + cs0); \
      ar[m4][1] = *reinterpret_cast<const bf16x8*>(p_ + ro_ + cs1); } } while (0)
#define LDB(buf, h) do { const unsigned short* p_ = &smem[32768 + ((buf) * 2 + (h)) * 8192]; \
    _Pragma("unroll") for (int n2 = 0; n2 < 2; ++n2) { \
      int ro_ = ((4 * n2 + wn) * 16 + fl) * 64; \
      br[n2][0] = *reinterpret_cast<const bf16x8*>(p_ + ro_ + cs0); \
      br[n2][1] = *reinterpret_cast<const bf16x8*>(p_ + ro_ + cs1); } } while (0)
#define QUAD(miH, niH) do { __builtin_amdgcn_s_setprio(1); \
    _Pragma("unroll") for (int m4 = 0; m4 < 4; ++m4) \
      _Pragma("unroll") for (int n2 = 0; n2 < 2; ++n2) \
        _Pragma("unroll") for (int s_ = 0; s_ < 2; ++s_) \
          acc[(miH) * 4 + m4][(niH) * 2 + n2] = __builtin_amdgcn_mfma_f32_16x16x32_bf16( \
              ar[m4][s_], br[n2][s_], acc[(miH) * 4 + m4][(niH) * 2 + n2], 0, 0, 0); \
    __builtin_amdgcn_s_setprio(0); } while (0)

  // prologue: T0 {A0,B0,B1,A1} -> buf0, T1 {A0,B1,A1} -> buf1 (B0 at I1).
  STGA(0, 0, 0); STGB(0, 0, 0); STGB(0, 1, 0); STGA(0, 1, 0);
  STGA(1, 0, 1); STGB(1, 1, 1); STGA(1, 1, 1);
  asm volatile("s_waitcnt vmcnt(6)" ::: "memory");   // T0 fully landed
  BAR();

  #pragma unroll 1
  for (int it = 0; it < 4; ++it) {
    const int t1 = 2 * it + 1, t2 = 2 * it + 2, t3 = 2 * it + 3;
    // ph1: quad(0,0) buf0 | I1: t1.B0 -> buf1.B0 (last read prev ph8)
    LDA(0, 0); LDB(0, 0);
    STGB(1, 0, t1);
    BAR(); QUAD(0, 0); BAR();
    // ph2: quad(0,1) buf0 | I2: t2.A0 -> buf0.A0 (last read ph1)
    LDB(0, 1);
    if (t2 < 8) STGA(0, 0, t2);
    BAR(); QUAD(0, 1); BAR();
    // ph3: quad(1,1) buf0 | I3: t2.B1 -> buf0.B1 (last read ph2)
    LDA(0, 1);
    if (t2 < 8) STGB(0, 1, t2);
    BAR(); QUAD(1, 1); BAR();
    // ph4: quad(1,0) buf0 | I4: t2.A1 -> buf0.A1 (last read ph3)
    LDB(0, 0);
    if (t2 < 8) STGA(0, 1, t2);
    BAR(); QUAD(1, 0);
    if (it < 3) asm volatile("s_waitcnt vmcnt(6)" ::: "memory");
    else        asm volatile("s_waitcnt vmcnt(0)" ::: "memory");
    BAR();
    // ph5: quad(0,0) buf1 | I5: t2.B0 -> buf0.B0 (last read ph4)
    LDA(1, 0); LDB(1, 0);
    if (t2 < 8) STGB(0, 0, t2);
    BAR(); QUAD(0, 0); BAR();
    // ph6: quad(0,1) buf1 | I6: t3.A0 -> buf1.A0 (last read ph5)
    LDB(1, 1);
    if (t3 < 8) STGA(1, 0, t3);
    BAR(); QUAD(0, 1); BAR();
    // ph7: quad(1,1) buf1 | I7: t3.B1 -> buf1.B1 (last read ph6)
    LDA(1, 1);
    if (t3 < 8) STGB(1, 1, t3);
    BAR(); QUAD(1, 1); BAR();
    // ph8: quad(1,0) buf1 | I8: t3.A1 -> buf1.A1 (last read ph7)
    LDB(1, 0);
    if (t3 < 8) STGA(1, 1, t3);
    BAR(); QUAD(1, 0);
    asm volatile("s_waitcnt vmcnt(6)" ::: "memory");
    BAR();
  }
#undef BAR
#undef STGA
#undef STGB
#undef LDA
#undef LDB
#undef QUAD

  // ---- epilogue (hw gate)
  {
    const float* bias = z ? bias1 : bias0;
    const size_t MS = (size_t)B_ * S_ * D_;
    float bnl[2], bg[2]; int xs[2];
    #pragma unroll
    for (int np = 0; np < 2; ++np) {
      xs[np] = (blockIdx.x * 8 + np * 4 + wn) * 16 + fl;
      bnl[np] = bias[xs[np]];
      bg[np]  = bias[512 + xs[np]];
    }
    #pragma unroll
    for (int mi = 0; mi < 8; ++mi) {
      #pragma unroll
      for (int r = 0; r < 4; ++r) {
        int gr = bm + (2 * mi + wm) * 16 + fq * 4 + r;
        #pragma unroll
        for (int np = 0; np < 2; ++np) {
          float nl = fmaxf(acc[mi][2 * np][r] + bnl[np], 0.f);
          float g  = 1.f / (1.f + __expf(-(acc[mi][2 * np + 1][r] + bg[np])));
          float xv = us2f(A[(size_t)gr * 512 + xs[np]]);
          float res = g * xv + (1.f - g) * nl;
          if (EPI == 2) Cfp[(size_t)gr * 1024 + (size_t)z * 512 + xs[np]] = res;
          else Cbf[(size_t)z * MS + (size_t)gr * 512 + xs[np]] = f2us(res);
        }
      }
    }
  }
}

// ---------------------------------------------------------------------------
// Proj GEMM + fused rel-add (128^2 structure). A = ctx (2,8192,512) bf16.
__global__ __launch_bounds__(256) void k_gemm_proj(
    const unsigned short* __restrict__ ctx,
    const unsigned short* __restrict__ WTp,    // (2,512,512)
    const unsigned short* __restrict__ nin,    // (B,S2,512)
    const float* __restrict__ lb3, const float* __restrict__ rb3,
    const float* __restrict__ wrel0, const float* __restrict__ wrel1,
    unsigned short* __restrict__ hwx)          // (2,8192,512)
{
  __shared__ unsigned short smem[128 * 136];   // 34.8 KB; staging uses 32 KB
  unsigned short* As = smem;
  unsigned short* Bs = smem + 8192;
  const int K = 512, N = 512;
  const size_t MS = (size_t)B_ * S_ * D_;

  const int z = blockIdx.z;
  const unsigned short* A = ctx + (size_t)z * MS;
  const unsigned short* BT = WTp + (size_t)z * 512 * 512;
  const float* bias = z ? rb3 : lb3;
  const float* wrel = z ? wrel1 : wrel0;
  const int off = z * WIDTH_;

  const int tid = threadIdx.x;
  const int w = tid >> 6;
  const int l = tid & 63;
  const int bm = blockIdx.y * 128;
  const int bn = blockIdx.x * 128;
  const int wrow = (w >> 1) * 64;
  const int wcol = (w & 1) * 64;

  const int lr = l >> 3;
  const int sk = (((l & 7) ^ lr) & 7) * 8;
  const unsigned short* Ap = A + (size_t)(bm + w * 8 + lr) * K + sk;
  const unsigned short* Bp = BT + (size_t)(bn + w * 8 + lr) * K + sk;
  unsigned short* lA = &As[w * 512];
  unsigned short* lB = &Bs[w * 512];
  const size_t K32 = (size_t)32 * K;

  const int fl = l & 15;
  const int fq = l >> 4;
  const int fx = fl & 7;

  f32x4 acc[4][4];
  #pragma unroll
  for (int mi = 0; mi < 4; ++mi)
    #pragma unroll
    for (int ni = 0; ni < 4; ++ni) acc[mi][ni] = (f32x4){0.f, 0.f, 0.f, 0.f};

  for (int k0 = 0; k0 < K; k0 += 64) {
    #pragma unroll
    for (int r = 0; r < 4; ++r) {
      async16(Ap + k0 + r * K32, lA + r * 2048);
      async16(Bp + k0 + r * K32, lB + r * 2048);
    }
    __syncthreads();
    #pragma unroll
    for (int s = 0; s < 2; ++s) {
      bf16x8 af[4], bfr[4];
      #pragma unroll
      for (int mi = 0; mi < 4; ++mi)
        af[mi] = *reinterpret_cast<const bf16x8*>(
            &As[(wrow + mi * 16 + fl) * 64 + (((s * 4 + fq) ^ fx) * 8)]);
      #pragma unroll
      for (int ni = 0; ni < 4; ++ni)
        bfr[ni] = *reinterpret_cast<const bf16x8*>(
            &Bs[(wcol + ni * 16 + fl) * 64 + (((s * 4 + fq) ^ fx) * 8)]);
      #pragma unroll
      for (int mi = 0; mi < 4; ++mi)
        #pragma unroll
        for (int ni = 0; ni < 4; ++ni)
          acc[mi][ni] = __builtin_amdgcn_mfma_f32_16x16x32_bf16(
              af[mi], bfr[ni], acc[mi][ni], 0, 0, 0);
    }
    __syncthreads();
  }

  // stage bias-added tile into LDS (bf16, ld 136)
  float bv[4];
  #pragma unroll
  for (int ni = 0; ni < 4; ++ni) bv[ni] = bias[bn + wcol + ni * 16 + fl];
  const int rbase = (l >> 4) * 4;
  #pragma unroll
  for (int mi = 0; mi < 4; ++mi)
    #pragma unroll
    for (int r = 0; r < 4; ++r)
      #pragma unroll
      for (int ni = 0; ni < 4; ++ni)
        smem[(wrow + mi * 16 + rbase + r) * 136 + wcol + ni * 16 + fl] =
            f2us(acc[mi][ni][r] + bv[ni]);
  __syncthreads();

  // cooperative rel-add: 16 threads per tile row, 8-col chunks
  const int trow = tid >> 4;
  const int tcol = (tid & 15) * 8;
  const float w0 = wrel[0], w1 = wrel[1], w2 = wrel[2], w3 = wrel[3],
              w4 = wrel[4], w5 = wrel[5], w6 = wrel[6], w7 = wrel[7],
              w8 = wrel[8];
  const float wj[9] = {w0, w1, w2, w3, w4, w5, w6, w7, w8};
  #pragma unroll
  for (int i = 0; i < 8; ++i) {
    int r = trow + i * 16;
    int gr = bm + r;
    int b = gr >> 10, s = gr & (S_ - 1);
    float a8[8];
    unpack8(*reinterpret_cast<const uint4*>(&smem[r * 136 + tcol]), a8);
    const unsigned short* np =
        nin + ((size_t)b * S2_ + off + s) * D_ + bn + tcol;
    #pragma unroll
    for (int j = 0; j < 9; ++j) {
      float nf[8];
      unpack8(*reinterpret_cast<const uint4*>(np + (size_t)j * D_), nf);
      #pragma unroll
      for (int e = 0; e < 8; ++e) a8[e] += wj[j] * nf[e];
    }
    uint4 o;
    o.x = pack2(a8[0], a8[1]); o.y = pack2(a8[2], a8[3]);
    o.z = pack2(a8[4], a8[5]); o.w = pack2(a8[6], a8[7]);
    *reinterpret_cast<uint4*>(
        hwx + (size_t)z * MS + (size_t)gr * D_ + bn + tcol) = o;
  }
}

// ---------------------------------------------------------------------------
// Windowed attention, compacted output. Wave = (dir, b, s), i = s + WIDTH.
// qkv ld 3072: dir*1536 + {q:0,k:512,v:1024}. ctx: (2,B,S,512).
__global__ __launch_bounds__(256) void k_attn_window(
    const unsigned short* __restrict__ qkv,
    unsigned short* __restrict__ ctx)
{
  int wid = (blockIdx.x * 256 + threadIdx.x) >> 6;   // dir*B*S + b*S + s
  int lane = threadIdx.x & 63;
  int s = wid & (S_ - 1);
  int b = (wid >> 10) & (B_ - 1);
  int dir = wid >> 13;
  int i = s + WIDTH_;

  const size_t base = (size_t)b * S2_ * 3072 + dir * 1536;
  const int c0 = lane * 8;

  float qf[8];
  unpack8(*reinterpret_cast<const uint4*>(qkv + base + (size_t)i * 3072 + c0), qf);

  float sc[10];
  float mx = -1e30f;
  #pragma unroll
  for (int t = 0; t < 10; ++t) {
    int j = (dir == 0) ? (i - 9 + t) : (i + t);
    float sv = -1e30f;
    if (j >= 0 && j < S2_) {
      float kf[8];
      unpack8(*reinterpret_cast<const uint4*>(
          qkv + base + (size_t)j * 3072 + 512 + c0), kf);
      float p = qf[0] * kf[0];
      #pragma unroll
      for (int e = 1; e < 8; ++e) p += qf[e] * kf[e];
      p += __shfl_xor(p, 1);
      p += __shfl_xor(p, 2);
      p += __shfl_xor(p, 4);
      sv = p * 0.125f;
    }
    sc[t] = sv;
    mx = fmaxf(mx, sv);
  }

  float denom = 0.f;
  #pragma unroll
  for (int t = 0; t < 10; ++t) {
    sc[t] = (sc[t] > -1e29f) ? __expf(sc[t] - mx) : 0.f;
    denom += sc[t];
  }
  float inv = 1.f / denom;

  float acc[8] = {0.f, 0.f, 0.f, 0.f, 0.f, 0.f, 0.f, 0.f};
  #pragma unroll
  for (int t = 0; t < 10; ++t) {
    int j = (dir == 0) ? (i - 9 + t) : (i + t);
    if (j >= 0 && j < S2_) {
      float vf[8];
      unpack8(*reinterpret_cast<const uint4*>(
          qkv + base + (size_t)j * 3072 + 1024 + c0), vf);
      float p = sc[t];
      #pragma unroll
      for (int e = 0; e < 8; ++e) acc[e] += p * vf[e];
    }
  }

  uint4 o;
  o.x = pack2(acc[0] * inv, acc[1] * inv);
  o.y = pack2(acc[2] * inv, acc[3] * inv);
  o.z = pack2(acc[4] * inv, acc[5] * inv);
  o.w = pack2(acc[6] * inv, acc[7] * inv);
  *reinterpret_cast<uint4*>(
      ctx + (((size_t)dir * B_ + b) * S_ + s) * D_ + c0) = o;
}

// ---------------------------------------------------------------------------
extern "C" void kernel_launch(void* const* d_in, const int* in_sizes, int n_in,
                              void* d_out, int out_size, void* d_ws, size_t ws_size,
                              hipStream_t stream) {
  const float* x    = (const float*)d_in[0];
  const float* lW   = (const float*)d_in[1];
  const float* lb   = (const float*)d_in[2];
  const float* rW   = (const float*)d_in[3];
  const float* rb   = (const float*)d_in[4];
  const float* lpad = (const float*)d_in[5];
  const float* rpad = (const float*)d_in[6];
  const float* lw   = (const float*)d_in[7];
  const float* rw   = (const float*)d_in[8];
  const float* lhwW = (const float*)d_in[9];
  const float* lhwb = (const float*)d_in[10];
  const float* rhwW = (const float*)d_in[11];
  const float* rhwb = (const float*)d_in[12];
  float* out = (float*)d_out;
  unsigned short* ws = (unsigned short*)d_ws;

  const size_t NIN  = (size_t)B_ * S2_ * D_;       // 4,259,840
  const size_t NQKV = (size_t)B_ * S2_ * 3072;     // 25,559,040
  const size_t MS   = (size_t)B_ * S_ * D_;        // 4,194,304
  const size_t DD   = (size_t)D_ * D_;             // 262,144
  const size_t LHW  = (size_t)1024 * 512;          // 524,288

  unsigned short* nin   = ws;
  unsigned short* qkv   = nin + NIN;
  unsigned short* ctx   = qkv + NQKV;              // (2,B,S,D)
  unsigned short* hwx   = ctx + 2 * MS;            // (2,B,S,D)
  unsigned short* hwy   = hwx + 2 * MS;            // (2,B,S,D)
  unsigned short* WTall = hwy + 2 * MS;            // (3072,512)
  unsigned short* WTp   = WTall + 6 * DD;          // (2,512,512)
  unsigned short* hWT   = WTp + 2 * DD;            // (2,2,1024,512)
  float* qkvbias        = (float*)(hWT + 4 * LHW); // 3072 fp32

  // --- prep: 1 dispatch ---
  k_prep<<<6188, 256, 0, stream>>>(x, lpad, rpad, lW, rW, lb, rb, lhwW, rhwW,
                                   WTall, WTp, hWT, nin, qkvbias);

  const int MQ = B_ * S2_;   // 8320

  // --- fused QKV both sides: (8320 x 3072), 128^2 2-phase ---
  {
    dim3 g(3072 / 128, MQ / 128, 1);   // (24, 65)
    k_gemm_mfma<<<g, 256, 0, stream>>>(nin, WTall, qkvbias, qkv, MQ, 3072, D_);
  }

  // --- attention, both sides, compacted ctx ---
  k_attn_window<<<(2 * B_ * S_) / 4, 256, 0, stream>>>(qkv, ctx);

  // --- proj + fused rel-add, z-batched over side (128^2 kernel) ---
  {
    dim3 g(D_ / 128, (B_ * S_) / 128, 2);   // (4, 64, 2)
    k_gemm_proj<<<g, 256, 0, stream>>>(ctx, WTp, nin, lb + 3 * D_, rb + 3 * D_,
                                       lw, rw, hwx);
  }

  // --- highway layers: 256^2 8-phase + fused gate, z-batched over side ---
  {
    dim3 g(1024 / 256, (B_ * S_) / 256, 2);   // (4, 32, 2)
    k_gemm256<1><<<g, 512, 0, stream>>>(hwx, MS, hWT, 2 * LHW,
                                        lhwb, rhwb, hwy, nullptr,
                                        B_ * S_, 1024);
    k_gemm256<2><<<g, 512, 0, stream>>>(hwy, MS, hWT + LHW, 2 * LHW,
                                        lhwb + 1024, rhwb + 1024,
                                        nullptr, out, B_ * S_, 1024);
  }
}